// Round 3
// baseline (535.808 us; speedup 1.0000x reference)
//
#include <hip/hip_runtime.h>
#include <hip/hip_bf16.h>

#define NTOK   4096
#define DMODEL 1024
#define DFF    4096
#define NEXP   8
#define TOPK   2
#define BM 256
#define BN 256
#define NSLOT   (NTOK*TOPK)            // 8192
#define MAXSLOT (NSLOT + NEXP*BM)      // 10240
#define MAXTILE (MAXSLOT/BM)           // 40

typedef __attribute__((ext_vector_type(8))) short bf16x8;
typedef __attribute__((ext_vector_type(4))) float f32x4;

__device__ __forceinline__ unsigned short f2bf(float f){
    union { float f; unsigned int u; } v; v.f = f;
    unsigned int r = (v.u + 0x7fffu + ((v.u >> 16) & 1u)) >> 16;
    return (unsigned short)r;
}
__device__ __forceinline__ float bf2f(unsigned short h){
    union { unsigned int u; float f; } v; v.u = ((unsigned int)h) << 16;
    return v.f;
}

__device__ __forceinline__ void gload16(const unsigned short* g, unsigned short* l){
    __builtin_amdgcn_global_load_lds(
        (const __attribute__((address_space(1))) void*)g,
        (__attribute__((address_space(3))) void*)l,
        16, 0, 0);
}

#define WAITLGKM() asm volatile("s_waitcnt lgkmcnt(0)" ::: "memory")
#define WAITVM4()  asm volatile("s_waitcnt vmcnt(4)" ::: "memory")
#define WAITVM0()  asm volatile("s_waitcnt vmcnt(0)" ::: "memory")
#define MFMA16(a,b,c) __builtin_amdgcn_mfma_f32_16x16x32_bf16(a,b,c,0,0,0)

// st_16x32 swizzled LDS read: logical (r, kcol) -> physical shorts index
__device__ __forceinline__ bf16x8 ldswz(const unsigned short* lds, int base, int r, int kcol){
    int idx = base + r*64 + kcol;
    idx ^= ((r>>2)&1) << 4;
    return *(const bf16x8*)&lds[idx];
}

// ------ fp32 [E][R][C] -> bf16 [E][C][R] transpose-convert ------
__global__ __launch_bounds__(256) void k_transpose_convert(const float* __restrict__ src,
                                                           unsigned short* __restrict__ dst,
                                                           int R, int C)
{
    __shared__ unsigned short tile[64][72];
    src += (size_t)blockIdx.z * R * C;
    dst += (size_t)blockIdx.z * R * C;
    int r0 = blockIdx.y * 64, c0 = blockIdx.x * 64;
    int t = threadIdx.x;
    int tr = t >> 4;          // 0..15
    int tc = (t & 15) * 4;    // 0..60
    #pragma unroll
    for(int i=0;i<4;i++){
        float4 v = *(const float4*)&src[(size_t)(r0 + tr + i*16)*C + c0 + tc];
        tile[tc+0][tr + i*16] = f2bf(v.x);
        tile[tc+1][tr + i*16] = f2bf(v.y);
        tile[tc+2][tr + i*16] = f2bf(v.z);
        tile[tc+3][tr + i*16] = f2bf(v.w);
    }
    __syncthreads();
    #pragma unroll
    for(int i=0;i<4;i++){
        ushort4 o;
        o.x = tile[tr + i*16][tc+0];
        o.y = tile[tr + i*16][tc+1];
        o.z = tile[tr + i*16][tc+2];
        o.w = tile[tr + i*16][tc+3];
        *(ushort4*)&dst[(size_t)(c0 + tr + i*16)*R + r0 + tc] = o;
    }
}

// ---------------- gating (+ fused x fp32->bf16 convert) ----------------
__global__ __launch_bounds__(256) void k_gate(const float* __restrict__ x,
                                              const float* __restrict__ Wg,
                                              const float* __restrict__ bg,
                                              unsigned short* __restrict__ Xb,
                                              int* __restrict__ token_e,
                                              float* __restrict__ token_w,
                                              int* __restrict__ cnt)
{
    int tid = threadIdx.x;
    // convert: block covers 4 tokens = 4096 floats = 1024 float4
    const float4* xs = (const float4*)x + (size_t)blockIdx.x * 1024;
    ushort4* xd = (ushort4*)Xb + (size_t)blockIdx.x * 1024;
    #pragma unroll
    for(int rep=0;rep<4;rep++){
        float4 v = xs[rep*256 + tid];
        ushort4 o; o.x=f2bf(v.x); o.y=f2bf(v.y); o.z=f2bf(v.z); o.w=f2bf(v.w);
        xd[rep*256 + tid] = o;
    }

    int wid = tid >> 6, lane = tid & 63;
    int t = blockIdx.x * 4 + wid;
    const float* xr = x + (size_t)t * DMODEL;
    float pe[NEXP];
    #pragma unroll
    for(int e=0;e<NEXP;e++) pe[e] = 0.f;
    for(int i=0;i<DMODEL/64;i++){
        int d = i*64 + lane;
        float xv = xr[d];
        const float* wr = Wg + (size_t)d * NEXP;
        #pragma unroll
        for(int e=0;e<NEXP;e++) pe[e] += xv * wr[e];
    }
    #pragma unroll
    for(int off=32; off>0; off>>=1){
        #pragma unroll
        for(int e=0;e<NEXP;e++) pe[e] += __shfl_xor(pe[e], off);
    }
    if(lane == 0){
        float lg[NEXP], mx = -1e30f;
        #pragma unroll
        for(int e=0;e<NEXP;e++){ lg[e] = pe[e] + bg[e]; mx = fmaxf(mx, lg[e]); }
        float pr[NEXP];
        #pragma unroll
        for(int e=0;e<NEXP;e++) pr[e] = expf(lg[e] - mx);
        int e0 = 0; float p0 = pr[0];
        #pragma unroll
        for(int e=1;e<NEXP;e++) if(pr[e] > p0){ p0 = pr[e]; e0 = e; }
        int e1 = -1; float p1 = -1.f;
        #pragma unroll
        for(int e=0;e<NEXP;e++) if(e != e0 && pr[e] > p1){ p1 = pr[e]; e1 = e; }
        float dn = p0 + p1;
        token_e[2*t]   = e0; token_w[2*t]   = p0/dn;
        token_e[2*t+1] = e1; token_w[2*t+1] = p1/dn;
        atomicAdd(&cnt[e0], 1); atomicAdd(&cnt[e1], 1);
    }
}

// ---------------- prefix + tile table + pad-fill + scatter (one block) ----------------
__global__ __launch_bounds__(256) void k_prefix_scatter(const int* __restrict__ cnt,
                                                        const int* __restrict__ token_e,
                                                        const float* __restrict__ token_w,
                                                        int* __restrict__ tile_e,
                                                        int* __restrict__ tile_row0,
                                                        int* __restrict__ tile_valid,
                                                        int* __restrict__ slot_token,
                                                        float* __restrict__ slot_w,
                                                        int* __restrict__ slot_of)
{
    __shared__ int sb[NEXP], scur[NEXP];
    int tid = threadIdx.x;
    if(tid == 0){
        int off = 0, nt = 0;
        for(int e=0;e<NEXP;e++){
            sb[e] = off; scur[e] = 0;
            int c = cnt[e];
            for(int r=0;r<c;r+=BM){
                tile_e[nt] = e; tile_row0[nt] = off + r;
                tile_valid[nt] = (c - r < BM) ? (c - r) : BM;
                nt++;
            }
            off += ((c + BM - 1)/BM)*BM;
        }
        for(int i=nt;i<MAXTILE;i++){ tile_e[i]=0; tile_row0[i]=0; tile_valid[i]=0; }
    }
    for(int s=tid; s<MAXSLOT; s+=256) slot_token[s] = 0;  // safe gather addr for pad rows
    __syncthreads();
    for(int i=tid; i<NSLOT; i+=256){
        int e = token_e[i];
        int s = sb[e] + atomicAdd(&scur[e], 1);
        slot_token[s] = i >> 1;
        slot_w[s] = token_w[i];
        slot_of[i] = s;
    }
}

// ---------------- grouped GEMM: 256x256 tile, 8-wave, 4-phase/K-tile, counted vmcnt ----------------
// A: bf16 lda==K (GATHER: row via slot_token). B: bf16 [E][N][K]. Out bf16 [slot][N].
template<bool GATHER, bool GELU>
__global__ __launch_bounds__(512, 2) void k_gemm(const unsigned short* __restrict__ A,
                                                 const unsigned short* __restrict__ Bw,
                                                 const float* __restrict__ bias,
                                                 const int* __restrict__ tile_e,
                                                 const int* __restrict__ tile_row0,
                                                 const int* __restrict__ tile_valid,
                                                 const int* __restrict__ slot_token,
                                                 const float* __restrict__ slot_w,
                                                 unsigned short* __restrict__ Out,
                                                 int K, int N)
{
    int tb = blockIdx.x;
    int valid = tile_valid[tb];
    if(valid == 0) return;
    int e = tile_e[tb], row0 = tile_row0[tb];
    int n0 = blockIdx.y * BN;
    const unsigned short* Be = Bw + (size_t)e * N * K;

    __shared__ unsigned short lds[65536];   // [buf:2][A|B][256][64] bf16 = 128 KB

    int tid = threadIdx.x;
    int lane = tid & 63, wid = tid >> 6;
    int wm = wid >> 2, wn = wid & 3;
    int rl = lane & 15, g = lane >> 4;

    // staging: thread covers (half h, round l): row r = h*128 + l*64 + (tid>>3), chunk cc = tid&7
    // pre-swizzled source chunk (st_16x32 involution): cc ^ ((r>>2)&1)<<1; (r>>2)&1 == (tid>>5)&1
    int r8  = tid >> 3;
    int ccs = (tid & 7) ^ (((tid >> 5) & 1) << 1);
    const unsigned short* asrc[2][2];
    const unsigned short* bsrc[2][2];
    #pragma unroll
    for(int h=0;h<2;h++){
        #pragma unroll
        for(int l=0;l<2;l++){
            int r = h*128 + l*64 + r8;
            size_t ar = GATHER ? (size_t)slot_token[row0 + r] * (size_t)K
                               : (size_t)(row0 + r) * (size_t)K;
            asrc[h][l] = A  + ar + ccs*8;
            bsrc[h][l] = Be + (size_t)(n0 + r)*K + ccs*8;
        }
    }
    int ldst = tid * 8;

#define SA(kt,h,l) gload16(asrc[h][l] + (kt)*64, &lds[(((kt)&1)<<15) + ((h)<<13) + ((l)<<12) + ldst])
#define SB(kt,h,l) gload16(bsrc[h][l] + (kt)*64, &lds[(((kt)&1)<<15) + 16384 + ((h)<<13) + ((l)<<12) + ldst])

    // prologue: T0 fully (A h0,h1 + B h0,h1), T1 B-halves  (12 loads)
    SA(0,0,0); SA(0,0,1); SA(0,1,0); SA(0,1,1);
    SB(0,0,0); SB(0,0,1); SB(0,1,0); SB(0,1,1);
    SB(1,0,0); SB(1,0,1); SB(1,1,0); SB(1,1,1);

    f32x4 acc[8][4];
    #pragma unroll
    for(int i=0;i<8;i++)
        #pragma unroll
        for(int j=0;j<4;j++) acc[i][j] = (f32x4){0.f,0.f,0.f,0.f};

    WAITVM4();                          // T0 landed (T1's 4 B-loads may fly)
    __builtin_amdgcn_s_barrier();

    int NK = K >> 6;
    bf16x8 af[4][2], bfv[4][2];

    for(int k=0;k<NK;k++){
        int bufo = (k & 1) << 15;
        bool stA = (k+1 < NK);          // stage T(k+1) A-halves at P1,P2 (other buffer)
        bool stB = (k+2 < NK);          // stage T(k+2) B-halves at P3,P4 (this buffer, B read done at P2)

        // ---- P1: read A(mh0) + B(n0,n1); MFMA quadrant (mh0, nh0)
        #pragma unroll
        for(int m=0;m<4;m++){
            af[m][0] = ldswz(lds, bufo, wm*128 + m*16 + rl, g*8);
            af[m][1] = ldswz(lds, bufo, wm*128 + m*16 + rl, 32 + g*8);
        }
        #pragma unroll
        for(int n=0;n<2;n++){
            bfv[n][0] = ldswz(lds, bufo + 16384, wn*64 + n*16 + rl, g*8);
            bfv[n][1] = ldswz(lds, bufo + 16384, wn*64 + n*16 + rl, 32 + g*8);
        }
        if(stA){ SA(k+1,0,0); SA(k+1,0,1); }
        __builtin_amdgcn_s_barrier();
        WAITLGKM();
        __builtin_amdgcn_s_setprio(1);
        #pragma unroll
        for(int m=0;m<4;m++)
            #pragma unroll
            for(int n=0;n<2;n++){
                acc[m][n] = MFMA16(af[m][0], bfv[n][0], acc[m][n]);
                acc[m][n] = MFMA16(af[m][1], bfv[n][1], acc[m][n]);
            }
        __builtin_amdgcn_s_setprio(0);
        __builtin_amdgcn_s_barrier();

        // ---- P2: read B(n2,n3); MFMA (mh0, nh1)
        #pragma unroll
        for(int n=2;n<4;n++){
            bfv[n][0] = ldswz(lds, bufo + 16384, wn*64 + n*16 + rl, g*8);
            bfv[n][1] = ldswz(lds, bufo + 16384, wn*64 + n*16 + rl, 32 + g*8);
        }
        if(stA){ SA(k+1,1,0); SA(k+1,1,1); }
        __builtin_amdgcn_s_barrier();
        WAITLGKM();
        __builtin_amdgcn_s_setprio(1);
        #pragma unroll
        for(int m=0;m<4;m++)
            #pragma unroll
            for(int n=2;n<4;n++){
                acc[m][n] = MFMA16(af[m][0], bfv[n][0], acc[m][n]);
                acc[m][n] = MFMA16(af[m][1], bfv[n][1], acc[m][n]);
            }
        __builtin_amdgcn_s_setprio(0);
        __builtin_amdgcn_s_barrier();

        // ---- P3: read A(mh1); MFMA (mh1, nh0)
        #pragma unroll
        for(int m=0;m<4;m++){
            af[m][0] = ldswz(lds, bufo, wm*128 + 64 + m*16 + rl, g*8);
            af[m][1] = ldswz(lds, bufo, wm*128 + 64 + m*16 + rl, 32 + g*8);
        }
        if(stB){ SB(k+2,0,0); SB(k+2,0,1); }
        __builtin_amdgcn_s_barrier();
        WAITLGKM();
        __builtin_amdgcn_s_setprio(1);
        #pragma unroll
        for(int m=0;m<4;m++)
            #pragma unroll
            for(int n=0;n<2;n++){
                acc[4+m][n] = MFMA16(af[m][0], bfv[n][0], acc[4+m][n]);
                acc[4+m][n] = MFMA16(af[m][1], bfv[n][1], acc[4+m][n]);
            }
        __builtin_amdgcn_s_setprio(0);
        __builtin_amdgcn_s_barrier();

        // ---- P4: MFMA (mh1, nh1); counted vmcnt gate
        if(stB){ SB(k+2,1,0); SB(k+2,1,1); }
        __builtin_amdgcn_s_barrier();
        __builtin_amdgcn_s_setprio(1);
        #pragma unroll
        for(int m=0;m<4;m++)
            #pragma unroll
            for(int n=2;n<4;n++){
                acc[4+m][n] = MFMA16(af[m][0], bfv[n][0], acc[4+m][n]);
                acc[4+m][n] = MFMA16(af[m][1], bfv[n][1], acc[4+m][n]);
            }
        __builtin_amdgcn_s_setprio(0);
        if(stB)      { WAITVM4(); }     // all but T(k+3)'s 2 B-stages landed -> T(k+1) ready
        else if(stA) { WAITVM0(); }     // last gate: T(NK-1) fully landed
        __builtin_amdgcn_s_barrier();
    }
#undef SA
#undef SB

    const float* be = bias + (size_t)e * N;
    #pragma unroll
    for(int mi=0;mi<8;mi++){
        int rbase = wm*128 + mi*16 + g*4;
        #pragma unroll
        for(int j=0;j<4;j++){
            int r = rbase + j;
            if(r >= valid) continue;
            size_t grow = (size_t)(row0 + r);
            float wsc = GELU ? 0.f : slot_w[grow];
            #pragma unroll
            for(int n=0;n<4;n++){
                int col = n0 + wn*64 + n*16 + rl;
                float v = acc[mi][n][j] + be[col];
                if(GELU) v = 0.5f * v * (1.f + erff(v * 0.70710678118654752f));
                else     v *= wsc;
                Out[grow * (size_t)N + col] = f2bf(v);
            }
        }
    }
}

// ---------------- combine: out[t] = Y[slot0] + Y[slot1] (already gate-scaled) ----------------
__global__ __launch_bounds__(256) void k_combine(const int* __restrict__ slot_of,
                                                 const unsigned short* __restrict__ Y,
                                                 float* __restrict__ out)
{
    int i = blockIdx.x*256 + threadIdx.x;
    int t  = i >> 8;
    int cg = i & 255;
    int s0 = slot_of[2*t], s1 = slot_of[2*t+1];
    uint2 a = *((const uint2*)(Y + (size_t)s0*DMODEL) + cg);
    uint2 b = *((const uint2*)(Y + (size_t)s1*DMODEL) + cg);
    float4 o;
    o.x = bf2f((unsigned short)(a.x & 0xffffu)) + bf2f((unsigned short)(b.x & 0xffffu));
    o.y = bf2f((unsigned short)(a.x >> 16))     + bf2f((unsigned short)(b.x >> 16));
    o.z = bf2f((unsigned short)(a.y & 0xffffu)) + bf2f((unsigned short)(b.y & 0xffffu));
    o.w = bf2f((unsigned short)(a.y >> 16))     + bf2f((unsigned short)(b.y >> 16));
    *((float4*)(out + (size_t)t*DMODEL) + cg) = o;
}

extern "C" void kernel_launch(void* const* d_in, const int* in_sizes, int n_in,
                              void* d_out, int out_size, void* d_ws, size_t ws_size,
                              hipStream_t stream)
{
    const float* x  = (const float*)d_in[0];
    const float* W1 = (const float*)d_in[1];
    const float* b1 = (const float*)d_in[2];
    const float* W2 = (const float*)d_in[3];
    const float* b2 = (const float*)d_in[4];
    const float* Wg = (const float*)d_in[5];
    const float* bg = (const float*)d_in[6];
    float* out = (float*)d_out;

    char* p = (char*)d_ws;
    auto alloc = [&](size_t bytes)->char*{
        char* r = p; p += (bytes + 255) & ~(size_t)255; return r;
    };
    unsigned short* W1t = (unsigned short*)alloc((size_t)NEXP*DFF*DMODEL*2);   // [E][DFF][DMODEL]
    unsigned short* W2t = (unsigned short*)alloc((size_t)NEXP*DMODEL*DFF*2);   // [E][DMODEL][DFF]
    unsigned short* Xb  = (unsigned short*)alloc((size_t)NTOK*DMODEL*2);
    unsigned short* H   = (unsigned short*)alloc((size_t)MAXSLOT*DFF*2);
    unsigned short* Y   = W1t;  // alias: W1t dead after GEMM1; Y written by GEMM2
    int*   slot_token = (int*)alloc(MAXSLOT*4);
    float* slot_w     = (float*)alloc(MAXSLOT*4);
    int*   slot_of    = (int*)alloc(NSLOT*4);
    int*   token_e    = (int*)alloc(NSLOT*4);
    float* token_w    = (float*)alloc(NSLOT*4);
    int*   cnt        = (int*)alloc(32);
    int*   tile_e     = (int*)alloc(MAXTILE*4);
    int*   tile_row0  = (int*)alloc(MAXTILE*4);
    int*   tile_valid = (int*)alloc(MAXTILE*4);
    (void)ws_size; (void)in_sizes; (void)n_in; (void)out_size;

    hipMemsetAsync(cnt, 0, 32, stream);
    k_gate<<<NTOK/4, 256, 0, stream>>>(x, Wg, bg, Xb, token_e, token_w, cnt);
    k_transpose_convert<<<dim3(DFF/64, DMODEL/64, NEXP), 256, 0, stream>>>(W1, W1t, DMODEL, DFF);
    k_transpose_convert<<<dim3(DMODEL/64, DFF/64, NEXP), 256, 0, stream>>>(W2, W2t, DFF, DMODEL);
    k_prefix_scatter<<<1, 256, 0, stream>>>(cnt, token_e, token_w,
                                            tile_e, tile_row0, tile_valid,
                                            slot_token, slot_w, slot_of);
    k_gemm<true, true ><<<dim3(MAXTILE, DFF/BN),    512, 0, stream>>>(
        Xb, W1t, b1, tile_e, tile_row0, tile_valid, slot_token, slot_w, H, DMODEL, DFF);
    k_gemm<false,false><<<dim3(MAXTILE, DMODEL/BN), 512, 0, stream>>>(
        H,  W2t, b2, tile_e, tile_row0, tile_valid, slot_token, slot_w, Y, DFF, DMODEL);
    k_combine<<<NTOK*DMODEL/4/256, 256, 0, stream>>>(slot_of, Y, out);
}

// Round 4
// 532.377 us; speedup vs baseline: 1.0064x; 1.0064x over previous
//
#include <hip/hip_runtime.h>
#include <hip/hip_bf16.h>

#define NTOK   4096
#define DMODEL 1024
#define DFF    4096
#define NEXP   8
#define TOPK   2
#define BM 256
#define BN 256
#define NSLOT   (NTOK*TOPK)            // 8192
#define MAXSLOT (NSLOT + NEXP*BM)      // 10240
#define MAXTILE (MAXSLOT/BM)           // 40

typedef __attribute__((ext_vector_type(8))) short bf16x8;
typedef __attribute__((ext_vector_type(4))) float f32x4;

__device__ __forceinline__ unsigned short f2bf(float f){
    union { float f; unsigned int u; } v; v.f = f;
    unsigned int r = (v.u + 0x7fffu + ((v.u >> 16) & 1u)) >> 16;
    return (unsigned short)r;
}
__device__ __forceinline__ float bf2f(unsigned short h){
    union { unsigned int u; float f; } v; v.u = ((unsigned int)h) << 16;
    return v.f;
}

__device__ __forceinline__ void gload16(const unsigned short* g, unsigned short* l){
    __builtin_amdgcn_global_load_lds(
        (const __attribute__((address_space(1))) void*)g,
        (__attribute__((address_space(3))) void*)l,
        16, 0, 0);
}

#define WAITLGKM() asm volatile("s_waitcnt lgkmcnt(0)" ::: "memory")
#define WAITVM8()  asm volatile("s_waitcnt vmcnt(8)" ::: "memory")
#define WAITVM0()  asm volatile("s_waitcnt vmcnt(0)" ::: "memory")
#define MFMA16(a,b,c) __builtin_amdgcn_mfma_f32_16x16x32_bf16(a,b,c,0,0,0)

// full 3-bit XOR swizzle (G4 recipe): byte ^= (row&7)<<4  ==  shorts ^= (row&7)<<3.
// 16-lane read phase (rows r..r+15, fixed kcol) -> 8 distinct 16B slots x 2 lanes = conflict-free.
__device__ __forceinline__ bf16x8 ldswz(const unsigned short* lds, int base, int r, int kcol){
    int idx = base + r*64 + (kcol ^ ((r & 7) << 3));
    return *(const bf16x8*)&lds[idx];
}

// ------ fp32 [E][R][C] -> bf16 [E][C][R] transpose-convert ------
__global__ __launch_bounds__(256) void k_transpose_convert(const float* __restrict__ src,
                                                           unsigned short* __restrict__ dst,
                                                           int R, int C)
{
    __shared__ unsigned short tile[64][72];
    src += (size_t)blockIdx.z * R * C;
    dst += (size_t)blockIdx.z * R * C;
    int r0 = blockIdx.y * 64, c0 = blockIdx.x * 64;
    int t = threadIdx.x;
    int tr = t >> 4;          // 0..15
    int tc = (t & 15) * 4;    // 0..60
    #pragma unroll
    for(int i=0;i<4;i++){
        float4 v = *(const float4*)&src[(size_t)(r0 + tr + i*16)*C + c0 + tc];
        tile[tc+0][tr + i*16] = f2bf(v.x);
        tile[tc+1][tr + i*16] = f2bf(v.y);
        tile[tc+2][tr + i*16] = f2bf(v.z);
        tile[tc+3][tr + i*16] = f2bf(v.w);
    }
    __syncthreads();
    #pragma unroll
    for(int i=0;i<4;i++){
        ushort4 o;
        o.x = tile[tr + i*16][tc+0];
        o.y = tile[tr + i*16][tc+1];
        o.z = tile[tr + i*16][tc+2];
        o.w = tile[tr + i*16][tc+3];
        *(ushort4*)&dst[(size_t)(c0 + tr + i*16)*R + r0 + tc] = o;
    }
}

// ---------------- gating (+ fused x fp32->bf16 convert) ----------------
__global__ __launch_bounds__(256) void k_gate(const float* __restrict__ x,
                                              const float* __restrict__ Wg,
                                              const float* __restrict__ bg,
                                              unsigned short* __restrict__ Xb,
                                              int* __restrict__ token_e,
                                              float* __restrict__ token_w,
                                              int* __restrict__ cnt)
{
    int tid = threadIdx.x;
    const float4* xs = (const float4*)x + (size_t)blockIdx.x * 1024;
    ushort4* xd = (ushort4*)Xb + (size_t)blockIdx.x * 1024;
    #pragma unroll
    for(int rep=0;rep<4;rep++){
        float4 v = xs[rep*256 + tid];
        ushort4 o; o.x=f2bf(v.x); o.y=f2bf(v.y); o.z=f2bf(v.z); o.w=f2bf(v.w);
        xd[rep*256 + tid] = o;
    }

    int wid = tid >> 6, lane = tid & 63;
    int t = blockIdx.x * 4 + wid;
    const float* xr = x + (size_t)t * DMODEL;
    float pe[NEXP];
    #pragma unroll
    for(int e=0;e<NEXP;e++) pe[e] = 0.f;
    for(int i=0;i<DMODEL/64;i++){
        int d = i*64 + lane;
        float xv = xr[d];
        const float* wr = Wg + (size_t)d * NEXP;
        #pragma unroll
        for(int e=0;e<NEXP;e++) pe[e] += xv * wr[e];
    }
    #pragma unroll
    for(int off=32; off>0; off>>=1){
        #pragma unroll
        for(int e=0;e<NEXP;e++) pe[e] += __shfl_xor(pe[e], off);
    }
    if(lane == 0){
        float lg[NEXP], mx = -1e30f;
        #pragma unroll
        for(int e=0;e<NEXP;e++){ lg[e] = pe[e] + bg[e]; mx = fmaxf(mx, lg[e]); }
        float pr[NEXP];
        #pragma unroll
        for(int e=0;e<NEXP;e++) pr[e] = expf(lg[e] - mx);
        int e0 = 0; float p0 = pr[0];
        #pragma unroll
        for(int e=1;e<NEXP;e++) if(pr[e] > p0){ p0 = pr[e]; e0 = e; }
        int e1 = -1; float p1 = -1.f;
        #pragma unroll
        for(int e=0;e<NEXP;e++) if(e != e0 && pr[e] > p1){ p1 = pr[e]; e1 = e; }
        float dn = p0 + p1;
        token_e[2*t]   = e0; token_w[2*t]   = p0/dn;
        token_e[2*t+1] = e1; token_w[2*t+1] = p1/dn;
        atomicAdd(&cnt[e0], 1); atomicAdd(&cnt[e1], 1);
    }
}

// ---------------- prefix + tile table + pad-fill + scatter (one block) ----------------
__global__ __launch_bounds__(256) void k_prefix_scatter(const int* __restrict__ cnt,
                                                        const int* __restrict__ token_e,
                                                        const float* __restrict__ token_w,
                                                        int* __restrict__ tile_e,
                                                        int* __restrict__ tile_row0,
                                                        int* __restrict__ tile_valid,
                                                        int* __restrict__ slot_token,
                                                        float* __restrict__ slot_w,
                                                        int* __restrict__ slot_of)
{
    __shared__ int sb[NEXP], scur[NEXP];
    int tid = threadIdx.x;
    if(tid == 0){
        int off = 0, nt = 0;
        for(int e=0;e<NEXP;e++){
            sb[e] = off; scur[e] = 0;
            int c = cnt[e];
            for(int r=0;r<c;r+=BM){
                tile_e[nt] = e; tile_row0[nt] = off + r;
                tile_valid[nt] = (c - r < BM) ? (c - r) : BM;
                nt++;
            }
            off += ((c + BM - 1)/BM)*BM;
        }
        for(int i=nt;i<MAXTILE;i++){ tile_e[i]=0; tile_row0[i]=0; tile_valid[i]=0; }
    }
    for(int s=tid; s<MAXSLOT; s+=256) slot_token[s] = 0;  // safe gather addr for pad rows
    __syncthreads();
    for(int i=tid; i<NSLOT; i+=256){
        int e = token_e[i];
        int s = sb[e] + atomicAdd(&scur[e], 1);
        slot_token[s] = i >> 1;
        slot_w[s] = token_w[i];
        slot_of[i] = s;
    }
}

// ---------------- grouped GEMM: 256x256, 8-wave, 4-phase/K-tile, 2-tile-deep pipeline ----------------
// A: bf16 lda==K (GATHER: row via slot_token). B: bf16 [E][N][K]. Out bf16 [slot][N].
template<bool GATHER, bool GELU>
__global__ __launch_bounds__(512, 2) void k_gemm(const unsigned short* __restrict__ A,
                                                 const unsigned short* __restrict__ Bw,
                                                 const float* __restrict__ bias,
                                                 const int* __restrict__ tile_e,
                                                 const int* __restrict__ tile_row0,
                                                 const int* __restrict__ tile_valid,
                                                 const int* __restrict__ slot_token,
                                                 const float* __restrict__ slot_w,
                                                 unsigned short* __restrict__ Out,
                                                 int K, int N)
{
    int tb = blockIdx.x;
    int valid = tile_valid[tb];
    if(valid == 0) return;
    int e = tile_e[tb], row0 = tile_row0[tb];
    int n0 = blockIdx.y * BN;
    const unsigned short* Be = Bw + (size_t)e * N * K;

    __shared__ unsigned short lds[65536];   // [buf:2][A|B][256][64] bf16 = 128 KB

    int tid = threadIdx.x;
    int lane = tid & 63, wid = tid >> 6;
    int wm = wid >> 2, wn = wid & 3;
    int rl = lane & 15, g = lane >> 4;

    // staging: thread covers (half h, round l): row r = h*128 + l*64 + (tid>>3), phys chunk tid&7.
    // source chunk pre-swizzled with the same 3-bit involution: (tid&7) ^ (r&7), r&7 == (tid>>3)&7.
    int r8  = tid >> 3;
    int ccs = (tid & 7) ^ (r8 & 7);
    const unsigned short* asrc[2][2];
    const unsigned short* bsrc[2][2];
    #pragma unroll
    for(int h=0;h<2;h++){
        #pragma unroll
        for(int l=0;l<2;l++){
            int r = h*128 + l*64 + r8;
            size_t ar = GATHER ? (size_t)slot_token[row0 + r] * (size_t)K
                               : (size_t)(row0 + r) * (size_t)K;
            asrc[h][l] = A  + ar + ccs*8;
            bsrc[h][l] = Be + (size_t)(n0 + r)*K + ccs*8;
        }
    }
    int ldst = tid * 8;

#define SA(kt,h,l) gload16(asrc[h][l] + (kt)*64, &lds[(((kt)&1)<<15) + ((h)<<13) + ((l)<<12) + ldst])
#define SB(kt,h,l) gload16(bsrc[h][l] + (kt)*64, &lds[(((kt)&1)<<15) + 16384 + ((h)<<13) + ((l)<<12) + ldst])

    // prologue: T0 fully (8 loads), then T1 fully (8 loads)
    SA(0,0,0); SA(0,0,1); SA(0,1,0); SA(0,1,1);
    SB(0,0,0); SB(0,0,1); SB(0,1,0); SB(0,1,1);
    SA(1,0,0); SA(1,0,1); SA(1,1,0); SA(1,1,1);
    SB(1,0,0); SB(1,0,1); SB(1,1,0); SB(1,1,1);

    f32x4 acc[8][4];
    #pragma unroll
    for(int i=0;i<8;i++)
        #pragma unroll
        for(int j=0;j<4;j++) acc[i][j] = (f32x4){0.f,0.f,0.f,0.f};

    WAITVM8();                          // T0 landed (T1's 8 loads may stay in flight)
    __builtin_amdgcn_s_barrier();

    int NK = K >> 6;
    bf16x8 af[4][2], bfv[4][2];

    for(int k=0;k<NK;k++){
        int bufo = (k & 1) << 15;
        bool stg = (k+2 < NK);          // stage all of T(k+2) at P3/P4

        // ---- P1: ds_read A(mh0) + B(n0,n1); MFMA quadrant (mh0, nh0)
        #pragma unroll
        for(int m=0;m<4;m++){
            af[m][0] = ldswz(lds, bufo, wm*128 + m*16 + rl, g*8);
            af[m][1] = ldswz(lds, bufo, wm*128 + m*16 + rl, 32 + g*8);
        }
        #pragma unroll
        for(int n=0;n<2;n++){
            bfv[n][0] = ldswz(lds, bufo + 16384, wn*64 + n*16 + rl, g*8);
            bfv[n][1] = ldswz(lds, bufo + 16384, wn*64 + n*16 + rl, 32 + g*8);
        }
        __builtin_amdgcn_s_barrier();
        WAITLGKM();
        __builtin_amdgcn_s_setprio(1);
        #pragma unroll
        for(int m=0;m<4;m++)
            #pragma unroll
            for(int n=0;n<2;n++){
                acc[m][n] = MFMA16(af[m][0], bfv[n][0], acc[m][n]);
                acc[m][n] = MFMA16(af[m][1], bfv[n][1], acc[m][n]);
            }
        __builtin_amdgcn_s_setprio(0);
        __builtin_amdgcn_s_barrier();

        // ---- P2: ds_read B(n2,n3); MFMA (mh0, nh1)
        #pragma unroll
        for(int n=2;n<4;n++){
            bfv[n][0] = ldswz(lds, bufo + 16384, wn*64 + n*16 + rl, g*8);
            bfv[n][1] = ldswz(lds, bufo + 16384, wn*64 + n*16 + rl, 32 + g*8);
        }
        __builtin_amdgcn_s_barrier();
        WAITLGKM();
        __builtin_amdgcn_s_setprio(1);
        #pragma unroll
        for(int m=0;m<4;m++)
            #pragma unroll
            for(int n=2;n<4;n++){
                acc[m][n] = MFMA16(af[m][0], bfv[n][0], acc[m][n]);
                acc[m][n] = MFMA16(af[m][1], bfv[n][1], acc[m][n]);
            }
        __builtin_amdgcn_s_setprio(0);
        __builtin_amdgcn_s_barrier();

        // ---- P3: ds_read A(mh1); stage B(k+2) h0 (B-buf reads finished at end-P2 barrier); MFMA (mh1, nh0)
        #pragma unroll
        for(int m=0;m<4;m++){
            af[m][0] = ldswz(lds, bufo, wm*128 + 64 + m*16 + rl, g*8);
            af[m][1] = ldswz(lds, bufo, wm*128 + 64 + m*16 + rl, 32 + g*8);
        }
        if(stg){ SB(k+2,0,0); SB(k+2,0,1); }
        __builtin_amdgcn_s_barrier();
        WAITLGKM();
        __builtin_amdgcn_s_setprio(1);
        #pragma unroll
        for(int m=0;m<4;m++)
            #pragma unroll
            for(int n=0;n<2;n++){
                acc[4+m][n] = MFMA16(af[m][0], bfv[n][0], acc[4+m][n]);
                acc[4+m][n] = MFMA16(af[m][1], bfv[n][1], acc[4+m][n]);
            }
        __builtin_amdgcn_s_setprio(0);
        __builtin_amdgcn_s_barrier();

        // ---- P4: stage B(k+2) h1 + A(k+2) all (A-buf reads finished at end-P3 barrier);
        //          MFMA (mh1, nh1); counted gate vmcnt(8) -> T(k+1) fully landed
        if(stg){ SB(k+2,1,0); SB(k+2,1,1); SA(k+2,0,0); SA(k+2,0,1); SA(k+2,1,0); SA(k+2,1,1); }
        __builtin_amdgcn_s_barrier();
        __builtin_amdgcn_s_setprio(1);
        #pragma unroll
        for(int m=0;m<4;m++)
            #pragma unroll
            for(int n=2;n<4;n++){
                acc[4+m][n] = MFMA16(af[m][0], bfv[n][0], acc[4+m][n]);
                acc[4+m][n] = MFMA16(af[m][1], bfv[n][1], acc[4+m][n]);
            }
        __builtin_amdgcn_s_setprio(0);
        if(stg)           { WAITVM8(); }   // keep T(k+2)'s 8 in flight; all older landed
        else if(k+1 < NK) { WAITVM0(); }   // last gate before final tile
        __builtin_amdgcn_s_barrier();
    }
#undef SA
#undef SB

    const float* be = bias + (size_t)e * N;
    #pragma unroll
    for(int mi=0;mi<8;mi++){
        int rbase = wm*128 + mi*16 + g*4;
        #pragma unroll
        for(int j=0;j<4;j++){
            int r = rbase + j;
            if(r >= valid) continue;
            size_t grow = (size_t)(row0 + r);
            float wsc = GELU ? 0.f : slot_w[grow];
            #pragma unroll
            for(int n=0;n<4;n++){
                int col = n0 + wn*64 + n*16 + rl;
                float v = acc[mi][n][j] + be[col];
                if(GELU) v = 0.5f * v * (1.f + erff(v * 0.70710678118654752f));
                else     v *= wsc;
                Out[grow * (size_t)N + col] = f2bf(v);
            }
        }
    }
}

// ---------------- combine: out[t] = Y[slot0] + Y[slot1] (already gate-scaled) ----------------
__global__ __launch_bounds__(256) void k_combine(const int* __restrict__ slot_of,
                                                 const unsigned short* __restrict__ Y,
                                                 float* __restrict__ out)
{
    int i = blockIdx.x*256 + threadIdx.x;
    int t  = i >> 8;
    int cg = i & 255;
    int s0 = slot_of[2*t], s1 = slot_of[2*t+1];
    uint2 a = *((const uint2*)(Y + (size_t)s0*DMODEL) + cg);
    uint2 b = *((const uint2*)(Y + (size_t)s1*DMODEL) + cg);
    float4 o;
    o.x = bf2f((unsigned short)(a.x & 0xffffu)) + bf2f((unsigned short)(b.x & 0xffffu));
    o.y = bf2f((unsigned short)(a.x >> 16))     + bf2f((unsigned short)(b.x >> 16));
    o.z = bf2f((unsigned short)(a.y & 0xffffu)) + bf2f((unsigned short)(b.y & 0xffffu));
    o.w = bf2f((unsigned short)(a.y >> 16))     + bf2f((unsigned short)(b.y >> 16));
    *((float4*)(out + (size_t)t*DMODEL) + cg) = o;
}

extern "C" void kernel_launch(void* const* d_in, const int* in_sizes, int n_in,
                              void* d_out, int out_size, void* d_ws, size_t ws_size,
                              hipStream_t stream)
{
    const float* x  = (const float*)d_in[0];
    const float* W1 = (const float*)d_in[1];
    const float* b1 = (const float*)d_in[2];
    const float* W2 = (const float*)d_in[3];
    const float* b2 = (const float*)d_in[4];
    const float* Wg = (const float*)d_in[5];
    const float* bg = (const float*)d_in[6];
    float* out = (float*)d_out;

    char* p = (char*)d_ws;
    auto alloc = [&](size_t bytes)->char*{
        char* r = p; p += (bytes + 255) & ~(size_t)255; return r;
    };
    unsigned short* W1t = (unsigned short*)alloc((size_t)NEXP*DFF*DMODEL*2);   // [E][DFF][DMODEL]
    unsigned short* W2t = (unsigned short*)alloc((size_t)NEXP*DMODEL*DFF*2);   // [E][DMODEL][DFF]
    unsigned short* Xb  = (unsigned short*)alloc((size_t)NTOK*DMODEL*2);
    unsigned short* H   = (unsigned short*)alloc((size_t)MAXSLOT*DFF*2);
    unsigned short* Y   = W1t;  // alias: W1t dead after GEMM1; Y written by GEMM2
    int*   slot_token = (int*)alloc(MAXSLOT*4);
    float* slot_w     = (float*)alloc(MAXSLOT*4);
    int*   slot_of    = (int*)alloc(NSLOT*4);
    int*   token_e    = (int*)alloc(NSLOT*4);
    float* token_w    = (float*)alloc(NSLOT*4);
    int*   cnt        = (int*)alloc(32);
    int*   tile_e     = (int*)alloc(MAXTILE*4);
    int*   tile_row0  = (int*)alloc(MAXTILE*4);
    int*   tile_valid = (int*)alloc(MAXTILE*4);
    (void)ws_size; (void)in_sizes; (void)n_in; (void)out_size;

    hipMemsetAsync(cnt, 0, 32, stream);
    k_gate<<<NTOK/4, 256, 0, stream>>>(x, Wg, bg, Xb, token_e, token_w, cnt);
    k_transpose_convert<<<dim3(DFF/64, DMODEL/64, NEXP), 256, 0, stream>>>(W1, W1t, DMODEL, DFF);
    k_transpose_convert<<<dim3(DMODEL/64, DFF/64, NEXP), 256, 0, stream>>>(W2, W2t, DFF, DMODEL);
    k_prefix_scatter<<<1, 256, 0, stream>>>(cnt, token_e, token_w,
                                            tile_e, tile_row0, tile_valid,
                                            slot_token, slot_w, slot_of);
    k_gemm<true, true ><<<dim3(MAXTILE, DFF/BN),    512, 0, stream>>>(
        Xb, W1t, b1, tile_e, tile_row0, tile_valid, slot_token, slot_w, H, DMODEL, DFF);
    k_gemm<false,false><<<dim3(MAXTILE, DMODEL/BN), 512, 0, stream>>>(
        H,  W2t, b2, tile_e, tile_row0, tile_valid, slot_token, slot_w, Y, DFF, DMODEL);
    k_combine<<<NTOK*DMODEL/4/256, 256, 0, stream>>>(slot_of, Y, out);
}

// Round 5
// 502.592 us; speedup vs baseline: 1.0661x; 1.0593x over previous
//
#include <hip/hip_runtime.h>
#include <hip/hip_bf16.h>

#define NTOK   4096
#define DMODEL 1024
#define DFF    4096
#define NEXP   8
#define TOPK   2
#define BM 128
#define BN 128
#define BK 64
#define NSLOT   (NTOK*TOPK)            // 8192
#define MAXSLOT (NSLOT + NEXP*BM)      // 9216
#define MAXTILE (MAXSLOT/BM)           // 72

typedef __attribute__((ext_vector_type(8))) short bf16x8;
typedef __attribute__((ext_vector_type(8))) unsigned short u16x8;
typedef __attribute__((ext_vector_type(4))) float f32x4;

__device__ __forceinline__ unsigned short f2bf(float f){
    union { float f; unsigned int u; } v; v.f = f;
    unsigned int r = (v.u + 0x7fffu + ((v.u >> 16) & 1u)) >> 16;
    return (unsigned short)r;
}

__device__ __forceinline__ void gload16(const unsigned short* g, unsigned short* l){
    __builtin_amdgcn_global_load_lds(
        (const __attribute__((address_space(1))) void*)g,
        (__attribute__((address_space(3))) void*)l,
        16, 0, 0);
}

// ------ fp32 [E][R][C] -> bf16 [E][C][R] transpose-convert ------
// 64x64 tiles; float4 loads (16B/lane); ushort8 stores (16B/lane).
// tile stride 72 shorts = 144B (16B-aligned rows, non-pow2 bank spread).
__global__ __launch_bounds__(256) void k_transpose_convert(const float* __restrict__ src,
                                                           unsigned short* __restrict__ dst,
                                                           int R, int C)
{
    __shared__ unsigned short tile[64][72];
    src += (size_t)blockIdx.z * R * C;
    dst += (size_t)blockIdx.z * R * C;
    int r0 = blockIdx.y * 64, c0 = blockIdx.x * 64;
    int t = threadIdx.x;
    int tr = t >> 4;          // 0..15
    int tc = (t & 15) * 4;    // 0..60
    #pragma unroll
    for(int i=0;i<4;i++){
        float4 v = *(const float4*)&src[(size_t)(r0 + tr + i*16)*C + c0 + tc];
        tile[tc+0][tr + i*16] = f2bf(v.x);
        tile[tc+1][tr + i*16] = f2bf(v.y);
        tile[tc+2][tr + i*16] = f2bf(v.z);
        tile[tc+3][tr + i*16] = f2bf(v.w);
    }
    __syncthreads();
    int rr  = t >> 3;         // 0..31
    int cc8 = (t & 7) * 8;    // 0..56
    #pragma unroll
    for(int i=0;i<2;i++){
        u16x8 o = *(const u16x8*)&tile[rr + i*32][cc8];
        *(u16x8*)&dst[(size_t)(c0 + rr + i*32)*R + r0 + cc8] = o;
    }
}

// ---------------- gating (+ fused x fp32->bf16 convert) ----------------
__global__ __launch_bounds__(256) void k_gate(const float* __restrict__ x,
                                              const float* __restrict__ Wg,
                                              const float* __restrict__ bg,
                                              unsigned short* __restrict__ Xb,
                                              int* __restrict__ token_e,
                                              float* __restrict__ token_w,
                                              int* __restrict__ cnt)
{
    int tid = threadIdx.x;
    const float4* xs = (const float4*)x + (size_t)blockIdx.x * 1024;
    ushort4* xd = (ushort4*)Xb + (size_t)blockIdx.x * 1024;
    #pragma unroll
    for(int rep=0;rep<4;rep++){
        float4 v = xs[rep*256 + tid];
        ushort4 o; o.x=f2bf(v.x); o.y=f2bf(v.y); o.z=f2bf(v.z); o.w=f2bf(v.w);
        xd[rep*256 + tid] = o;
    }

    int wid = tid >> 6, lane = tid & 63;
    int t = blockIdx.x * 4 + wid;
    const float* xr = x + (size_t)t * DMODEL;
    float pe[NEXP];
    #pragma unroll
    for(int e=0;e<NEXP;e++) pe[e] = 0.f;
    for(int i=0;i<DMODEL/64;i++){
        int d = i*64 + lane;
        float xv = xr[d];
        const float* wr = Wg + (size_t)d * NEXP;
        #pragma unroll
        for(int e=0;e<NEXP;e++) pe[e] += xv * wr[e];
    }
    #pragma unroll
    for(int off=32; off>0; off>>=1){
        #pragma unroll
        for(int e=0;e<NEXP;e++) pe[e] += __shfl_xor(pe[e], off);
    }
    if(lane == 0){
        float lg[NEXP], mx = -1e30f;
        #pragma unroll
        for(int e=0;e<NEXP;e++){ lg[e] = pe[e] + bg[e]; mx = fmaxf(mx, lg[e]); }
        float pr[NEXP];
        #pragma unroll
        for(int e=0;e<NEXP;e++) pr[e] = expf(lg[e] - mx);
        int e0 = 0; float p0 = pr[0];
        #pragma unroll
        for(int e=1;e<NEXP;e++) if(pr[e] > p0){ p0 = pr[e]; e0 = e; }
        int e1 = -1; float p1 = -1.f;
        #pragma unroll
        for(int e=0;e<NEXP;e++) if(e != e0 && pr[e] > p1){ p1 = pr[e]; e1 = e; }
        float dn = p0 + p1;
        token_e[2*t]   = e0; token_w[2*t]   = p0/dn;
        token_e[2*t+1] = e1; token_w[2*t+1] = p1/dn;
        atomicAdd(&cnt[e0], 1); atomicAdd(&cnt[e1], 1);
    }
}

// ---------------- prefix + tile table + pad-fill + scatter (one block) ----------------
__global__ __launch_bounds__(256) void k_prefix_scatter(const int* __restrict__ cnt,
                                                        const int* __restrict__ token_e,
                                                        const float* __restrict__ token_w,
                                                        int* __restrict__ tile_e,
                                                        int* __restrict__ tile_row0,
                                                        int* __restrict__ tile_valid,
                                                        int* __restrict__ slot_token,
                                                        float* __restrict__ slot_w)
{
    __shared__ int sb[NEXP], scur[NEXP];
    int tid = threadIdx.x;
    if(tid == 0){
        int off = 0, nt = 0;
        for(int e=0;e<NEXP;e++){
            sb[e] = off; scur[e] = 0;
            int c = cnt[e];
            for(int r=0;r<c;r+=BM){
                tile_e[nt] = e; tile_row0[nt] = off + r;
                tile_valid[nt] = (c - r < BM) ? (c - r) : BM;
                nt++;
            }
            off += ((c + BM - 1)/BM)*BM;
        }
        for(int i=nt;i<MAXTILE;i++){ tile_e[i]=0; tile_row0[i]=0; tile_valid[i]=0; }
    }
    for(int s=tid; s<MAXSLOT; s+=256) slot_token[s] = 0;  // safe gather addr for pad rows
    __syncthreads();
    for(int i=tid; i<NSLOT; i+=256){
        int e = token_e[i];
        int s = sb[e] + atomicAdd(&scur[e], 1);
        slot_token[s] = i >> 1;
        slot_w[s] = token_w[i];
    }
}

// ---------------- grouped GEMM tile kernel (m97 structure, proven round-2) ----------------
// A: bf16, lda == K. GATHER: A row r -> slot_token[row0+r]. else A row = row0+r.
// B: bf16 [E][N][K] (pre-transposed). 
// GELU: OutH[slot][N] = gelu(acc+bias) (bf16).  else: atomicAdd fp32 into
// outF[token][col] of slot_w[slot]*(acc+bias) — fused combine (2 commutative adds/elem).
template<bool GATHER, bool GELU>
__global__ __launch_bounds__(256) void k_gemm(const unsigned short* __restrict__ A,
                                              const unsigned short* __restrict__ Bw,
                                              const float* __restrict__ bias,
                                              const int* __restrict__ tile_e,
                                              const int* __restrict__ tile_row0,
                                              const int* __restrict__ tile_valid,
                                              const int* __restrict__ slot_token,
                                              const float* __restrict__ slot_w,
                                              unsigned short* __restrict__ OutH,
                                              float* __restrict__ outF,
                                              int K, int N)
{
    int tid = blockIdx.x;
    int valid = tile_valid[tid];
    if(valid == 0) return;
    int e = tile_e[tid];
    int row0 = tile_row0[tid];
    int n0 = blockIdx.y * BN;
    const unsigned short* Be = Bw + (size_t)e * N * K;

    __shared__ unsigned short As[BM*BK];
    __shared__ unsigned short Bs[BN*BK];

    int t = threadIdx.x;
    int lane = t & 63;
    int wid = t >> 6;
    int wr = wid >> 1, wc = wid & 1;

    // staging: thread t, issue i stages LDS chunk p = i*256+t (16B chunks)
    // row r = i*32 + (t>>3), phys chunk c = t&7; content = global chunk c ^ (r&7)
    int srow = t >> 3;                      // 0..31
    int csw  = (t & 7) ^ (srow & 7);        // swizzled source chunk
    const unsigned short* arow[4];
    const unsigned short* brow[4];
    #pragma unroll
    for(int i=0;i<4;i++){
        int r = i*32 + srow;
        size_t aoff;
        if(GATHER) aoff = (size_t)slot_token[row0 + r] * (size_t)K;
        else       aoff = (size_t)(row0 + r) * (size_t)K;
        arow[i] = A  + aoff + csw*8;
        brow[i] = Be + (size_t)(n0 + r)*K + csw*8;
    }
    unsigned short* alds = As + (size_t)t * 8;
    unsigned short* blds = Bs + (size_t)t * 8;

    f32x4 acc[4][4];
    #pragma unroll
    for(int m=0;m<4;m++)
        #pragma unroll
        for(int n=0;n<4;n++)
            acc[m][n] = (f32x4){0.f,0.f,0.f,0.f};

    int rl = lane & 15;
    int g  = lane >> 4;
    int rx = rl & 7;

    for(int k0=0;k0<K;k0+=BK){
        __syncthreads();   // previous compute done before LDS overwrite
        #pragma unroll
        for(int i=0;i<4;i++){
            gload16(arow[i] + k0, alds + i*2048);
            gload16(brow[i] + k0, blds + i*2048);
        }
        __syncthreads();   // compiler drains vmcnt(0) before barrier -> tile ready

        #pragma unroll
        for(int kb=0;kb<2;kb++){
            int sw = ((kb*4 + g) ^ rx) * 8;   // swizzled chunk offset (shorts)
            bf16x8 af[4], bfv[4];
            #pragma unroll
            for(int m=0;m<4;m++) af[m]  = *(const bf16x8*)&As[(wr*64 + m*16 + rl)*BK + sw];
            #pragma unroll
            for(int n=0;n<4;n++) bfv[n] = *(const bf16x8*)&Bs[(wc*64 + n*16 + rl)*BK + sw];
            #pragma unroll
            for(int m=0;m<4;m++)
                #pragma unroll
                for(int n=0;n<4;n++)
                    acc[m][n] = __builtin_amdgcn_mfma_f32_16x16x32_bf16(af[m], bfv[n], acc[m][n], 0, 0, 0);
        }
    }

    const float* be = bias + (size_t)e * N;
    #pragma unroll
    for(int m=0;m<4;m++){
        int rb = wr*64 + m*16 + ((lane>>4)<<2);
        #pragma unroll
        for(int j=0;j<4;j++){
            int r = rb + j;
            if(r >= valid) continue;
            size_t grow = (size_t)(row0 + r);
            if(GELU){
                #pragma unroll
                for(int n=0;n<4;n++){
                    int col = n0 + wc*64 + n*16 + rl;
                    float v = acc[m][n][j] + be[col];
                    v = 0.5f * v * (1.f + erff(v * 0.70710678118654752f));
                    OutH[grow * (size_t)N + col] = f2bf(v);
                }
            } else {
                float wsc = slot_w[grow];
                float* orow = outF + (size_t)slot_token[grow] * DMODEL;
                #pragma unroll
                for(int n=0;n<4;n++){
                    int col = n0 + wc*64 + n*16 + rl;
                    float v = (acc[m][n][j] + be[col]) * wsc;
                    atomicAdd(&orow[col], v);
                }
            }
        }
    }
}

extern "C" void kernel_launch(void* const* d_in, const int* in_sizes, int n_in,
                              void* d_out, int out_size, void* d_ws, size_t ws_size,
                              hipStream_t stream)
{
    const float* x  = (const float*)d_in[0];
    const float* W1 = (const float*)d_in[1];
    const float* b1 = (const float*)d_in[2];
    const float* W2 = (const float*)d_in[3];
    const float* b2 = (const float*)d_in[4];
    const float* Wg = (const float*)d_in[5];
    const float* bg = (const float*)d_in[6];
    float* out = (float*)d_out;

    char* p = (char*)d_ws;
    auto alloc = [&](size_t bytes)->char*{
        char* r = p; p += (bytes + 255) & ~(size_t)255; return r;
    };
    unsigned short* W1t = (unsigned short*)alloc((size_t)NEXP*DFF*DMODEL*2);   // [E][DFF][DMODEL]
    unsigned short* W2t = (unsigned short*)alloc((size_t)NEXP*DMODEL*DFF*2);   // [E][DMODEL][DFF]
    unsigned short* Xb  = (unsigned short*)alloc((size_t)NTOK*DMODEL*2);
    unsigned short* H   = (unsigned short*)alloc((size_t)MAXSLOT*DFF*2);
    int*   slot_token = (int*)alloc(MAXSLOT*4);
    float* slot_w     = (float*)alloc(MAXSLOT*4);
    int*   token_e    = (int*)alloc(NSLOT*4);
    float* token_w    = (float*)alloc(NSLOT*4);
    int*   cnt        = (int*)alloc(32);
    int*   tile_e     = (int*)alloc(MAXTILE*4);
    int*   tile_row0  = (int*)alloc(MAXTILE*4);
    int*   tile_valid = (int*)alloc(MAXTILE*4);
    (void)ws_size; (void)in_sizes; (void)n_in; (void)out_size;

    hipMemsetAsync(cnt, 0, 32, stream);
    hipMemsetAsync(out, 0, (size_t)NTOK*DMODEL*4, stream);   // fused-combine accumulator base
    k_gate<<<NTOK/4, 256, 0, stream>>>(x, Wg, bg, Xb, token_e, token_w, cnt);
    k_transpose_convert<<<dim3(DFF/64, DMODEL/64, NEXP), 256, 0, stream>>>(W1, W1t, DMODEL, DFF);
    k_transpose_convert<<<dim3(DMODEL/64, DFF/64, NEXP), 256, 0, stream>>>(W2, W2t, DFF, DMODEL);
    k_prefix_scatter<<<1, 256, 0, stream>>>(cnt, token_e, token_w,
                                            tile_e, tile_row0, tile_valid,
                                            slot_token, slot_w);
    k_gemm<true, true ><<<dim3(MAXTILE, DFF/BN),    256, 0, stream>>>(
        Xb, W1t, b1, tile_e, tile_row0, tile_valid, slot_token, slot_w, H, nullptr, DMODEL, DFF);
    k_gemm<false,false><<<dim3(MAXTILE, DMODEL/BN), 256, 0, stream>>>(
        H,  W2t, b2, tile_e, tile_row0, tile_valid, slot_token, slot_w, nullptr, out, DFF, DMODEL);
}